// Round 6
// baseline (200.184 us; speedup 1.0000x reference)
//
#include <hip/hip_runtime.h>

#define B 256
#define N 512
#define M 512
#define BM (B * M)   // 131072
#define NM (N * M)   // 262144

// ---------------------------------------------------------------------------
// k_xt: xT[n][b] = x[b][n].  64x64 tiles through padded LDS.
// ---------------------------------------------------------------------------
__global__ __launch_bounds__(256) void k_xt(const float* __restrict__ x,
                                            float* __restrict__ xT) {
    __shared__ float s[64][65];
    const int tx = threadIdx.x, ty = threadIdx.y;
    const int n0 = blockIdx.x * 64, b0 = blockIdx.y * 64;
    #pragma unroll
    for (int j = 0; j < 16; ++j) {
        int bl = ty * 16 + j;
        s[bl][tx] = x[(b0 + bl) * N + n0 + tx];
    }
    __syncthreads();
    #pragma unroll
    for (int j = 0; j < 16; ++j) {
        int nl = ty * 16 + j;
        xT[(n0 + nl) * B + b0 + tx] = s[tx][nl];
    }
}

// ---------------------------------------------------------------------------
// k_sums: sum_x[n] = sum_b x[b,n]; sum_w[m] = sum_n w[n,m]. f64, fixed order.
// ---------------------------------------------------------------------------
__global__ void k_sums(const float* __restrict__ x, const float* __restrict__ w,
                       float* __restrict__ sum_x, float* __restrict__ sum_w) {
    int i = blockIdx.x * 64 + threadIdx.x;  // 0..1023
    if (i < N) {
        double a0 = 0.0, a1 = 0.0, a2 = 0.0, a3 = 0.0;
        for (int b = 0; b < B; b += 4) {
            a0 += (double)x[(b + 0) * N + i];
            a1 += (double)x[(b + 1) * N + i];
            a2 += (double)x[(b + 2) * N + i];
            a3 += (double)x[(b + 3) * N + i];
        }
        sum_x[i] = (float)((a0 + a1) + (a2 + a3));
    } else {
        int m = i - N;
        double a0 = 0.0, a1 = 0.0, a2 = 0.0, a3 = 0.0;
        for (int n = 0; n < N; n += 4) {
            a0 += (double)w[(n + 0) * M + m];
            a1 += (double)w[(n + 1) * M + m];
            a2 += (double)w[(n + 2) * M + m];
            a3 += (double)w[(n + 3) * M + m];
        }
        sum_w[m] = (float)((a0 + a1) + (a2 + a3));
    }
}

// ---------------------------------------------------------------------------
// k_sortw: one block per column m; rank-based sort (all-pairs, 1 barrier).
//  pmT[m][n] = prefix max of w[0..n, m]           (Hillis-Steele, f32)
//  swT[m][j] = w[:, m] sorted ascending
//  psT[m][k] = f64 sum of k smallest (k=0..512, row stride 514, H-S f64)
// ---------------------------------------------------------------------------
__global__ __launch_bounds__(512) void k_sortw(const float* __restrict__ w,
                                               float* __restrict__ pmT,
                                               float* __restrict__ swT,
                                               double* __restrict__ psT) {
    const int m = blockIdx.x, tid = threadIdx.x;
    __shared__ float  s[512];
    __shared__ float  pm[512];
    __shared__ float  s2[512];
    __shared__ double ps[512];
    float v = w[tid * M + m];
    s[tid] = v;
    pm[tid] = v;
    __syncthreads();
    // ascending rank via all-pairs (stable: ties broken by original index)
    int rank = 0;
    #pragma unroll 8
    for (int j = 0; j < 512; ++j) {
        float u = s[j];
        rank += (u < v) || (u == v && j < tid);
    }
    s2[rank] = v;
    // inclusive prefix max over ORIGINAL order (Hillis-Steele)
    for (int off = 1; off < 512; off <<= 1) {
        float cur = pm[tid];
        float oth = (tid >= off) ? pm[tid - off] : -1.0f;
        __syncthreads();
        pm[tid] = fmaxf(cur, oth);
        __syncthreads();
    }
    pmT[m * 512 + tid] = pm[tid];
    __syncthreads();           // s2 fully written (covered by scan syncs too)
    float sv = s2[tid];
    swT[m * 512 + tid] = sv;
    ps[tid] = (double)sv;
    __syncthreads();
    // f64 inclusive prefix sum of sorted values
    for (int off = 1; off < 512; off <<= 1) {
        double cur = ps[tid];
        double oth = (tid >= off) ? ps[tid - off] : 0.0;
        __syncthreads();
        ps[tid] = cur + oth;
        __syncthreads();
    }
    if (tid == 0) psT[m * 514] = 0.0;
    psT[m * 514 + tid + 1] = ps[tid];
}

// ---------------------------------------------------------------------------
// k_sortx: per row b, x[b,:] sorted DESCENDING as uint2{n, bits(v)}.
// Rank-based (all-pairs), 1 barrier, 256 blocks x 512 threads.
// ---------------------------------------------------------------------------
__global__ __launch_bounds__(512) void k_sortx(const float* __restrict__ x,
                                               uint2* __restrict__ sxT) {
    const int b = blockIdx.x, tid = threadIdx.x;
    __shared__ float s[512];
    float v = x[b * N + tid];
    s[tid] = v;
    __syncthreads();
    int rank = 0;
    #pragma unroll 8
    for (int j = 0; j < 512; ++j) {
        float u = s[j];
        rank += (u > v) || (u == v && j < tid);
    }
    sxT[b * 512 + rank] = make_uint2((unsigned)tid, __float_as_uint(v));
}

// ---------------------------------------------------------------------------
// k_relxA: px[z][n,m] = sum_{b in chunk z(64)} min(x[b,n], t[b,m]). f32.
// Tile 32n x 32m; block (16,16) -> 2n x 2m per thread; LDS sub-chunks of 32 b.
// grid (16, 16, 4).  [unchanged from R5 big-branch: proven absmax 0]
// ---------------------------------------------------------------------------
__global__ __launch_bounds__(256) void k_relxA(const float* __restrict__ xT,
                                               const float* __restrict__ t,
                                               float* __restrict__ px) {
    const int tx = threadIdx.x, ty = threadIdx.y;
    const int m0 = blockIdx.x * 32, n0 = blockIdx.y * 32;
    const int bbase = blockIdx.z * 64;
    __shared__ float s_t[32][32];    // [b-local][m-local]
    __shared__ float s_xn[32][36];   // [n-local][b-local], pad breaks conflicts
    const int tid = ty * 16 + tx;
    const int sr = tid / 8, sc4 = (tid & 7) * 4;
    const int nA = ty * 2, nB = nA + 1;
    float a00 = 0.f, a01 = 0.f, a10 = 0.f, a11 = 0.f;
    for (int scnk = 0; scnk < 2; ++scnk) {
        const int bb = bbase + scnk * 32;
        __syncthreads();
        *(float4*)&s_t[sr][sc4]  = *(const float4*)&t[(bb + sr) * M + m0 + sc4];
        *(float4*)&s_xn[sr][sc4] = *(const float4*)&xT[(n0 + sr) * B + bb + sc4];
        __syncthreads();
        #pragma unroll 8
        for (int i = 0; i < 32; ++i) {
            float2 tv = *(const float2*)&s_t[i][tx * 2];
            float x0 = s_xn[nA][i];
            float x1 = s_xn[nB][i];
            a00 += fminf(x0, tv.x); a01 += fminf(x0, tv.y);
            a10 += fminf(x1, tv.x); a11 += fminf(x1, tv.y);
        }
    }
    const int base = blockIdx.z * NM;
    const int mA = m0 + tx * 2;
    px[base + (n0 + nA) * M + mA]     = a00;
    px[base + (n0 + nA) * M + mA + 1] = a01;
    px[base + (n0 + nB) * M + mA]     = a10;
    px[base + (n0 + nB) * M + mA + 1] = a11;
}

// ---------------------------------------------------------------------------
// k_relxB: rel_x[n,m] = (sum_z px[z]) / sum_x[n].  [same grouping as R5: 4]
// ---------------------------------------------------------------------------
__global__ void k_relxB(const float* __restrict__ px, const float* __restrict__ sum_x,
                        float* __restrict__ rel_x) {
    int e = (blockIdx.x * 256 + threadIdx.x) * 4;
    int n = e >> 9;
    float4 r = *(const float4*)&px[e];
    #pragma unroll
    for (int z = 1; z < 4; ++z) {
        float4 p = *(const float4*)&px[z * NM + e];
        r.x += p.x; r.y += p.y; r.z += p.z; r.w += p.w;
    }
    float sx = sum_x[n];
    r.x /= sx; r.y /= sx; r.z /= sx; r.w /= sx;
    *(float4*)&rel_x[e] = r;
}

// ---------------------------------------------------------------------------
// k_scan: per (b,m):
//  ind_w: scan x[b,:] in DESCENDING order; v=min(x,rel_x[n,m]); stop when all
//         lanes have x_(i) < best (later v <= x < best can't win or tie).
//         (v,-n) lexicographic update == exact first-occurrence argmax.
//  rel_w: k = lower_bound(swT[m], t) -> rw = psT[m][k] + t*(512-k) (f64)
//  ind_x: lower_bound(pmT[m], min(c, colmax))
// block (64,4): lane=m (rel_x gathers coalesced, sorted-x reads wave-uniform),
// ty=b. grid (8, 64).
// ---------------------------------------------------------------------------
__global__ __launch_bounds__(256) void k_scan(
        const float* __restrict__ x, const float* __restrict__ w,
        const float* __restrict__ t, const float* __restrict__ sum_w,
        const float* __restrict__ swT, const float* __restrict__ pmT,
        const double* __restrict__ psT, const uint2* __restrict__ sxT,
        const float* __restrict__ rel_x, float* __restrict__ out) {
    const int m = blockIdx.x * 64 + threadIdx.x;
    const int b = blockIdx.y * 4 + threadIdx.y;
    const int o = b * M + m;

    // --- ind_w: early-exit descending-x scan ---
    const uint2* sxr = sxT + b * 512;
    float bv = -1.0f;
    int bi = 0;
    for (int i = 0; i < 512; ++i) {
        uint2 e = sxr[i];                       // wave-uniform
        float xv = __uint_as_float(e.y);
        if (__ballot(xv >= bv) == 0) break;     // all lanes done
        int n = (int)e.x;
        float r = rel_x[n * M + m];             // coalesced gather
        float v = fminf(xv, r);
        if (v > bv || (v == bv && n < bi)) { bv = v; bi = n; }
    }

    // --- rel_w via sorted-CDF (f64 exact) ---
    const float tbm = t[o];
    const float* sw = swT + m * 512;
    int lo = 0, hi = 512;
    while (lo < hi) { int mid = (lo + hi) >> 1; if (sw[mid] >= tbm) hi = mid; else lo = mid + 1; }
    const int kk = lo;
    double rw = psT[m * 514 + kk] + (double)tbm * (double)(512 - kk);
    float c = (float)rw / sum_w[m];

    // --- ind_x via prefix-max binary search ---
    const float* pm = pmT + m * 512;
    float tgt = fminf(c, pm[511]);
    lo = 0; hi = 511;
    while (lo < hi) { int mid = (lo + hi) >> 1; if (pm[mid] >= tgt) hi = mid; else lo = mid + 1; }
    const int ind = lo;

    out[o]      = fminf(x[b * N + ind], w[ind * M + m]);  // chosen_x
    out[BM + o] = fminf(x[b * N + bi],  w[bi * M + m]);   // chosen_w
}

extern "C" void kernel_launch(void* const* d_in, const int* in_sizes, int n_in,
                              void* d_out, int out_size, void* d_ws, size_t ws_size,
                              hipStream_t stream) {
    const float* x = (const float*)d_in[0];  // (B, N)
    const float* w = (const float*)d_in[1];  // (N, M)
    const float* t = (const float*)d_in[2];  // (B, M)
    float* out = (float*)d_out;

    float* ws = (float*)d_ws;
    // layout (float offsets), ~11 MB total (ws is ~268 MB per R5 fill counter):
    float*  xT    = ws;                        // 131072
    float*  sum_x = ws + 131072;               // 512
    float*  sum_w = ws + 131584;               // 512
    float*  rel_x = ws + 132096;               // 262144
    float*  swT   = ws + 394240;               // 262144
    float*  pmT   = ws + 656384;               // 262144
    double* psT   = (double*)(ws + 918528);    // 512*514 doubles
    uint2*  sxT   = (uint2*)(ws + 1444864);    // B*512 uint2 = 262144 floats
    float*  px    = ws + 1707008;              // 4*NM floats

    k_xt   <<<dim3(N / 64, B / 64), dim3(64, 4), 0, stream>>>(x, xT);
    k_sums <<<dim3(16), dim3(64), 0, stream>>>(x, w, sum_x, sum_w);
    k_sortw<<<dim3(M), dim3(512), 0, stream>>>(w, pmT, swT, psT);
    k_sortx<<<dim3(B), dim3(512), 0, stream>>>(x, sxT);
    k_relxA<<<dim3(16, 16, 4), dim3(16, 16), 0, stream>>>(xT, t, px);
    k_relxB<<<dim3(NM / 1024), dim3(256), 0, stream>>>(px, sum_x, rel_x);
    k_scan <<<dim3(8, 64), dim3(64, 4), 0, stream>>>(x, w, t, sum_w, swT, pmT, psT, sxT, rel_x, out);
}

// Round 7
// 100.364 us; speedup vs baseline: 1.9946x; 1.9946x over previous
//
#include <hip/hip_runtime.h>

#define B 256
#define N 512
#define M 512
#define BM (B * M)   // 131072
#define NM (N * M)   // 262144

// ===========================================================================
// k_pre: all transposes + f64 column sums, one launch.
//  blk 0..31   : xT[n][b] = x[b][n]
//  blk 32..95  : wT[m][n] = w[n][m]
//  blk 96..127 : tT[m][b] = t[b][m]
//  blk 128     : sum_x (f64, bit-identical to R1..R6)
//  blk 129     : sum_w (f64, bit-identical to R1..R6)
// ===========================================================================
__device__ __forceinline__ void tile_tr(const float* __restrict__ src,
                                        float* __restrict__ dst,
                                        int R, int C, int r0, int c0, int tid) {
    __shared__ float s[64][65];
    const int tx = tid & 63, ty = tid >> 6;   // 8 rows each
    #pragma unroll
    for (int j = 0; j < 8; ++j) {
        int rl = ty * 8 + j;
        s[rl][tx] = src[(r0 + rl) * C + c0 + tx];
    }
    __syncthreads();
    #pragma unroll
    for (int j = 0; j < 8; ++j) {
        int cl = ty * 8 + j;
        dst[(c0 + cl) * R + r0 + tx] = s[tx][cl];
    }
}

__global__ __launch_bounds__(512) void k_pre(const float* __restrict__ x,
                                             const float* __restrict__ w,
                                             const float* __restrict__ t,
                                             float* __restrict__ xT,
                                             float* __restrict__ wT,
                                             float* __restrict__ tT,
                                             float* __restrict__ sum_x,
                                             float* __restrict__ sum_w) {
    const int blk = blockIdx.x, tid = threadIdx.x;
    if (blk < 32) {
        tile_tr(x, xT, B, N, (blk >> 3) * 64, (blk & 7) * 64, tid);
    } else if (blk < 96) {
        int id = blk - 32;
        tile_tr(w, wT, N, M, (id >> 3) * 64, (id & 7) * 64, tid);
    } else if (blk < 128) {
        int id = blk - 96;
        tile_tr(t, tT, B, M, (id >> 3) * 64, (id & 7) * 64, tid);
    } else if (blk == 128) {
        int i = tid;
        double a0 = 0, a1 = 0, a2 = 0, a3 = 0;
        for (int b = 0; b < B; b += 4) {
            a0 += (double)x[(b + 0) * N + i];
            a1 += (double)x[(b + 1) * N + i];
            a2 += (double)x[(b + 2) * N + i];
            a3 += (double)x[(b + 3) * N + i];
        }
        sum_x[i] = (float)((a0 + a1) + (a2 + a3));
    } else {
        int mm = tid;
        double a0 = 0, a1 = 0, a2 = 0, a3 = 0;
        for (int n = 0; n < N; n += 4) {
            a0 += (double)w[(n + 0) * M + mm];
            a1 += (double)w[(n + 1) * M + mm];
            a2 += (double)w[(n + 2) * M + mm];
            a3 += (double)w[(n + 3) * M + mm];
        }
        sum_w[mm] = (float)((a0 + a1) + (a2 + a3));
    }
}

// ===========================================================================
// k_relxA: px[z][m][n] = sum_{b in chunk z(64)} min(x[b,n], t[b,m]). f32.
// Accumulation bit-identical to R5/R6 (absmax 0 proven); stores TRANSPOSED
// so k_col's per-column reads are coalesced.
// ===========================================================================
__global__ __launch_bounds__(256) void k_relxA(const float* __restrict__ xT,
                                               const float* __restrict__ t,
                                               float* __restrict__ px) {
    const int tx = threadIdx.x, ty = threadIdx.y;
    const int m0 = blockIdx.x * 32, n0 = blockIdx.y * 32;
    const int bbase = blockIdx.z * 64;
    __shared__ float s_t[32][32];    // [b-local][m-local]
    __shared__ float s_xn[32][36];   // [n-local][b-local]
    const int tid = ty * 16 + tx;
    const int sr = tid / 8, sc4 = (tid & 7) * 4;
    const int nA = ty * 2, nB = nA + 1;
    float a00 = 0.f, a01 = 0.f, a10 = 0.f, a11 = 0.f;
    for (int scnk = 0; scnk < 2; ++scnk) {
        const int bb = bbase + scnk * 32;
        __syncthreads();
        *(float4*)&s_t[sr][sc4]  = *(const float4*)&t[(bb + sr) * M + m0 + sc4];
        *(float4*)&s_xn[sr][sc4] = *(const float4*)&xT[(n0 + sr) * B + bb + sc4];
        __syncthreads();
        #pragma unroll 8
        for (int i = 0; i < 32; ++i) {
            float2 tv = *(const float2*)&s_t[i][tx * 2];
            float x0 = s_xn[nA][i];
            float x1 = s_xn[nB][i];
            a00 += fminf(x0, tv.x); a01 += fminf(x0, tv.y);
            a10 += fminf(x1, tv.x); a11 += fminf(x1, tv.y);
        }
    }
    const int base = blockIdx.z * NM;
    const int mA = m0 + tx * 2;
    *(float2*)&px[base + mA * N + n0 + nA]       = make_float2(a00, a10);
    *(float2*)&px[base + (mA + 1) * N + n0 + nA] = make_float2(a01, a11);
}

// ===========================================================================
// k_col: one block per column m; everything column-local in LDS.
//  A) w: prefix-max pm (H-S, orig order) + 256-bucket value histogram:
//     exclusive base, bucket-ordered values, per-bucket f64 sums + prefix.
//     (Exact: float bucketing is monotone, partial bucket resolved per-elem.)
//  B) rel column (bit-identical to R5 relxB) bucketed DESCENDING with
//     per-bucket max as scan upper bound.
//  C) waves 0-3 (b=tid): ind_w scan in descending-rel order, exit when
//     bound < best for all lanes; exact first-occurrence via (v==bv&&n<bi).
//  D) waves 4-7 (b=tid-256): rel_w CDF query (exact count, f64 sum),
//     c=(float)rw/sum_w, ind_x = lower_bound(pm, min(c, pm[511])), chosen_x.
// ===========================================================================
__global__ __launch_bounds__(512) void k_col(
        const float* __restrict__ x, const float* __restrict__ xT,
        const float* __restrict__ wT, const float* __restrict__ tT,
        const float* __restrict__ px, const float* __restrict__ sum_x,
        const float* __restrict__ sum_w, float* __restrict__ out) {
    const int m = blockIdx.x, tid = threadIdx.x;

    __shared__ float  worig[512];
    __shared__ float  pm[512];
    __shared__ float  wsrt[512];
    __shared__ int    cnt[256];
    __shared__ int    cbase[256];
    __shared__ double bsumI[256];
    __shared__ float  redA[256];
    __shared__ float  redB[256];
    __shared__ float  srx_r[512];
    __shared__ int    srx_n[512];
    __shared__ float  srx_u[512];
    __shared__ int    rcnt[256];
    __shared__ int    rbase[256];
    __shared__ int    rbmax[256];

    // ---- loads: w column + rel column (bit-identical order to R5) ----
    const float wv = wT[m * N + tid];
    float rv;
    {
        float p = px[m * N + tid];
        p += px[NM + m * N + tid];
        p += px[2 * NM + m * N + tid];
        p += px[3 * NM + m * N + tid];
        rv = p / sum_x[tid];
    }
    worig[tid] = wv;
    pm[tid] = wv;
    srx_r[tid] = rv;                 // temp: original order, for reductions
    if (tid < 256) { cnt[tid] = 0; rcnt[tid] = 0; rbmax[tid] = 0; }
    __syncthreads();

    // ---- pm: H-S inclusive prefix max, original order ----
    for (int off = 1; off < 512; off <<= 1) {
        float cur = pm[tid];
        float oth = (tid >= off) ? pm[tid - off] : -1.0f;
        __syncthreads();
        pm[tid] = fmaxf(cur, oth);
        __syncthreads();
    }

    // ---- wmin + rel min (one pass), then rel max ----
    if (tid < 256) {
        redA[tid] = fminf(worig[tid], worig[tid + 256]);
        redB[tid] = fminf(srx_r[tid], srx_r[tid + 256]);
    }
    __syncthreads();
    for (int s2 = 128; s2 > 0; s2 >>= 1) {
        if (tid < s2) {
            redA[tid] = fminf(redA[tid], redA[tid + s2]);
            redB[tid] = fminf(redB[tid], redB[tid + s2]);
        }
        __syncthreads();
    }
    const float wmin = redA[0];
    const float rmin = redB[0];
    __syncthreads();
    if (tid < 256) redB[tid] = fmaxf(srx_r[tid], srx_r[tid + 256]);
    __syncthreads();
    for (int s2 = 128; s2 > 0; s2 >>= 1) {
        if (tid < s2) redB[tid] = fmaxf(redB[tid], redB[tid + s2]);
        __syncthreads();
    }
    const float rmax = redB[0];
    const float wmax = pm[511];

    // ---- histograms ----
    const float wscale = 255.0f / fmaxf(wmax - wmin, 1e-30f);
    int wk = (int)((wv - wmin) * wscale);
    wk = wk < 0 ? 0 : (wk > 255 ? 255 : wk);
    atomicAdd(&cnt[wk], 1);

    const float rscale = 255.0f / fmaxf(rmax - rmin, 1e-30f);
    int rk;
    { int kv = (int)((rv - rmin) * rscale); kv = kv < 0 ? 0 : (kv > 255 ? 255 : kv); rk = 255 - kv; }
    atomicAdd(&rcnt[rk], 1);
    atomicMax(&rbmax[rk], __float_as_int(rv));   // rv > 0: int-bit order valid
    __syncthreads();

    // ---- H-S prefix (both histograms), inclusive -> exclusive ----
    if (tid < 256) { cbase[tid] = cnt[tid]; rbase[tid] = rcnt[tid]; }
    __syncthreads();
    for (int off = 1; off < 256; off <<= 1) {
        int c1 = 0, c2 = 0, o1 = 0, o2 = 0;
        if (tid < 256) {
            c1 = cbase[tid]; c2 = rbase[tid];
            if (tid >= off) { o1 = cbase[tid - off]; o2 = rbase[tid - off]; }
        }
        __syncthreads();
        if (tid < 256) { cbase[tid] = c1 + o1; rbase[tid] = c2 + o2; }
        __syncthreads();
    }
    if (tid < 256) {
        cbase[tid] -= cnt[tid];
        rbase[tid] -= rcnt[tid];
        cnt[tid] = 0; rcnt[tid] = 0;     // reuse as slot counters
    }
    __syncthreads();

    // ---- scatter (bucket-ordered) ----
    {
        int p1 = cbase[wk] + atomicAdd(&cnt[wk], 1);
        wsrt[p1] = wv;
        int p2 = rbase[rk] + atomicAdd(&rcnt[rk], 1);
        srx_r[p2] = rv;
        srx_n[p2] = tid;
        srx_u[p2] = __int_as_float(rbmax[rk]);   // final since pre-barrier
    }
    __syncthreads();

    // ---- per-bucket f64 sums of w + H-S inclusive prefix ----
    if (tid < 256) {
        double s = 0.0;
        int st = cbase[tid], e = st + cnt[tid];
        for (int i = st; i < e; ++i) s += (double)wsrt[i];
        bsumI[tid] = s;
    }
    __syncthreads();
    for (int off = 1; off < 256; off <<= 1) {
        double cur = 0.0, oth = 0.0;
        if (tid < 256) { cur = bsumI[tid]; if (tid >= off) oth = bsumI[tid - off]; }
        __syncthreads();
        if (tid < 256) bsumI[tid] = cur + oth;
        __syncthreads();
    }

    if (tid < 256) {
        // ==== phase C: ind_w scan (waves 0-3, b = tid) ====
        const int b = tid;
        float bv = -1.0f; int bi = 0;
        for (int i = 0; i < 512; ++i) {
            float u = srx_u[i];                      // non-increasing bound
            if (__ballot(u >= bv) == 0ULL) break;    // all lanes finished
            float r = srx_r[i];
            int   n = srx_n[i];
            float xv = xT[n * B + b];                // coalesced
            float v = fminf(xv, r);
            if (v > bv || (v == bv && n < bi)) { bv = v; bi = n; }
        }
        out[BM + b * M + m] = fminf(x[b * N + bi], worig[bi]);   // chosen_w
    } else {
        // ==== phase D: rel_w CDF + ind_x (waves 4-7, b = tid-256) ====
        const int b = tid - 256;
        const float tbm = tT[m * B + b];             // coalesced
        float btf = (tbm - wmin) * wscale;
        int kk; double S;
        if (btf < 0.0f) { kk = 0; S = 0.0; }         // t below all w
        else {
            int bt = (int)btf; bt = bt > 255 ? 255 : bt;
            kk = cbase[bt];                          // exact: buckets<bt => w<t
            S = (bt > 0) ? bsumI[bt - 1] : 0.0;
            int e = cbase[bt] + cnt[bt];
            for (int i = cbase[bt]; i < e; ++i) {    // partial bucket, exact
                float v = wsrt[i];
                if (v < tbm) { ++kk; S += (double)v; }
            }
        }
        double rw = S + (double)tbm * (double)(512 - kk);
        float c = (float)rw / sum_w[m];
        float tgt = fminf(c, pm[511]);
        int lo = 0, hi = 511;
        while (lo < hi) { int mid = (lo + hi) >> 1; if (pm[mid] >= tgt) hi = mid; else lo = mid + 1; }
        const int ind = lo;
        out[b * M + m] = fminf(x[b * N + ind], worig[ind]);      // chosen_x
    }
}

extern "C" void kernel_launch(void* const* d_in, const int* in_sizes, int n_in,
                              void* d_out, int out_size, void* d_ws, size_t ws_size,
                              hipStream_t stream) {
    const float* x = (const float*)d_in[0];  // (B, N)
    const float* w = (const float*)d_in[1];  // (N, M)
    const float* t = (const float*)d_in[2];  // (B, M)
    float* out = (float*)d_out;

    float* ws = (float*)d_ws;
    float* xT    = ws;                 // 131072
    float* wT    = ws + 131072;        // 262144
    float* tT    = ws + 393216;        // 131072
    float* sum_x = ws + 524288;        // 512
    float* sum_w = ws + 524800;        // 512
    float* px    = ws + 525312;        // 4*NM = 1048576   (~6.3 MB total)

    k_pre  <<<130, 512, 0, stream>>>(x, w, t, xT, wT, tT, sum_x, sum_w);
    k_relxA<<<dim3(16, 16, 4), dim3(16, 16), 0, stream>>>(xT, t, px);
    k_col  <<<512, 512, 0, stream>>>(x, xT, wT, tT, px, sum_x, sum_w, out);
}